// Round 2
// baseline (319.230 us; speedup 1.0000x reference)
//
#include <hip/hip_runtime.h>
#include <hip/hip_bf16.h>

// Problem: B=16, S=2048, H=1024
//   a = encoder_outputs (B,S,H) f32
//   projh[b,o] = sum_h h[b,h]*W[o,h] + bias[o]
//   scores[b,s] = sum_o relu( sum_h a[b,s,h]*W[o,H+h] + projh[b,o] ) * v[o]
//   weights = softmax_s(scores); context[b,h] = sum_s weights[b,s]*a[b,s,h]
// Outputs concat: context (16*1024 f32) then weights (16*2048 f32)
//
// Round 7: prep's 32-us A-conversion pass is FUSED into the gemm. A is
// reg-staged from f32 (2x float4 -> f2bf -> ds_write_b128) into the exact
// byte layout gload_lds used to produce (read side untouched); nq==0 blocks
// write the bf16 back to Ab for the softmax/context kernel. B staging stays
// gload_lds. 8-phase counted-vmcnt schedule kept; ledger re-derived:
// vmcnt(2) at p1/p3 before AWRITE (retires the A-regs + the B-slot needed
// 2 phases later; newest-2 left = youngest B pair). Writeback stores are
// always younger than the needed set -> superset-retire safe.

typedef __bf16 bf16x8 __attribute__((ext_vector_type(8)));
typedef float floatx4 __attribute__((ext_vector_type(4)));

#define BB 16
#define SS 2048
#define HH 1024
#define MM (BB * SS)

#define GLB(p) ((const __attribute__((address_space(1))) void*)(p))
#define LDSP(p) ((__attribute__((address_space(3))) void*)(p))

__device__ inline ushort f2bf(float x) {
    uint32_t u = __builtin_bit_cast(uint32_t, x);
    u += 0x7FFFu + ((u >> 16) & 1u);   // round-to-nearest-even
    return (ushort)(u >> 16);
}

// ---------------- prep_all ----------------
// bids [0,256): projh; [256,320): convert_W; [320,336): zero sp0+ctx.
// (A-conversion removed -- fused into gemm staging.)
__global__ __launch_bounds__(256) void prep_all_kernel(
    const float* __restrict__ h, const float* __restrict__ W,
    const float* __restrict__ bias,
    float* __restrict__ projh, __bf16* __restrict__ Wb,
    float* __restrict__ sp0, float* __restrict__ ctx)
{
    int bid = blockIdx.x;
    int tid = threadIdx.x;
    if (bid < 256) {
        // projh: (16,1024) = h(16,1024) x W[:, :H]^T + bias
        int b = bid >> 4;
        int oc = bid & 15;
        __shared__ float hrow[HH];
        *(float4*)&hrow[tid * 4] = *(const float4*)(h + (size_t)b * HH + tid * 4);
        __syncthreads();
        int ol = tid >> 2;           // 0..63
        int kq = tid & 3;            // 0..3 (k quarter)
        int o = oc * 64 + ol;
        const float* wr = W + (size_t)o * (2 * HH) + kq * 256;
        const float* hb = hrow + kq * 256;
        float sum = 0.f;
        for (int k = 0; k < 256; k += 4) {
            float4 wv = *(const float4*)(wr + k);
            sum += hb[k] * wv.x + hb[k + 1] * wv.y + hb[k + 2] * wv.z + hb[k + 3] * wv.w;
        }
        sum += __shfl_xor(sum, 1);
        sum += __shfl_xor(sum, 2);
        if (kq == 0) projh[b * HH + o] = sum + bias[o];
    } else if (bid < 320) {
        // convert W[:, H:2H] -> Wb (1024x1024 bf16)
        int cb = bid - 256;
#pragma unroll
        for (int j = 0; j < 8; j++) {
            int g = cb * 2048 + tid + j * 256;
            int o = g >> 7;
            int k = (g & 127) * 8;
            const float* s = W + (size_t)o * (2 * HH) + HH + k;
            float4 x = *(const float4*)(s);
            float4 y = *(const float4*)(s + 4);
            union { ushort u[8]; uint4 v; } p;
            p.u[0] = f2bf(x.x); p.u[1] = f2bf(x.y); p.u[2] = f2bf(x.z); p.u[3] = f2bf(x.w);
            p.u[4] = f2bf(y.x); p.u[5] = f2bf(y.y); p.u[6] = f2bf(y.z); p.u[7] = f2bf(y.w);
            *(uint4*)(Wb + (size_t)o * HH + k) = p.v;
        }
    } else {
        // zero sp0 (32768 f32, fallback path) and ctx (16384 f32): 16 blocks
        int zb = bid - 320;
        float4 z = make_float4(0.f, 0.f, 0.f, 0.f);
        float* sp = sp0 + zb * 2048 + tid * 8;
        *(float4*)(sp) = z;
        *(float4*)(sp + 4) = z;
        *(float4*)(ctx + zb * 1024 + tid * 4) = z;
    }
}

// ---------------- main GEMM: 256x256 tile, 8 waves, BK=64, 8-phase schedule ----------------
// A: reg-staged from f32 (issue p1/p3, ds_write 2 phases later into the same
// linear layout gload_lds produced; nq==0 also stores bf16 to Ab). B: gload_lds
// ring, unchanged. Slots: A half-K (256x32 bf16 = 16KB) ring 0..3; B ditto at
// +32768 elems. (kt,half) -> slot 2*(kt&1)+half.
// Ledger (steady state, per wave; issue order p1:A-regs(4) p2:B(2) p3:A(4)
// p4:B(2)): p1 entry = [B(kt,k1)2, A(kt+1,k1)4, B(kt+1,k0)2]; vmcnt(2)
// retires B(kt,k1) (read p3) + A-regs (written now), leaves newest B pair.
// p3 symmetric. Writeback stores are issued inside AWRITE (older than the
// next phases' loads or at worst between them) -> retire set stays superset.
// Write-visibility: AWRITE drains at this phase's LGKM0, >=1 barrier before
// any reader (readers are >=4 phases behind the write).
__global__ __launch_bounds__(512, 2) void gemm_scores_kernel(
    const float* __restrict__ Af,     // (32768,1024) f32 encoder outputs
    const __bf16* __restrict__ Wb,    // (1024,1024) bf16 (cols H..2H of W)
    const float* __restrict__ projh,  // (16,1024) f32
    const float* __restrict__ vW,     // (1024) f32
    float* __restrict__ scores_part,  // (4, 32768) f32
    __bf16* __restrict__ Ab)          // (32768,1024) bf16 writeback (nq==0)
{
    __shared__ __bf16 smem[65536];    // 128 KB

    const int bid = blockIdx.x;
    const int m0 = (((bid >> 5) << 3) + (bid & 7)) * 256;  // 128 M-tiles
    const int nq = (bid >> 3) & 3;    // 4 blocks sharing an A M-tile differ in
    const int n0 = nq * 256;          // bits 3-4 -> same XCD (L2 A-tile share)
    const int bidx = m0 >> 11;        // batch index (256 divides 2048)

    const int tid = threadIdx.x;
    const int lane = tid & 63;
    const int wave = tid >> 6;        // 0..7
    const int wm = (wave & 1) * 128;  // wave tile: 128 (M) x 64 (N)
    const int wn = (wave >> 1) * 64;
    const int quad = lane >> 4;
    const int l16 = lane & 15;

    floatx4 acc[8][4];
    const floatx4 z = {0.f, 0.f, 0.f, 0.f};
#pragma unroll
    for (int i = 0; i < 8; i++)
#pragma unroll
        for (int j = 0; j < 4; j++) acc[i][j] = z;

    // staging thread map (same XOR-swizzled global source map as before; LDS
    // written linearly at tid*16B so the read offsets are unchanged)
    const int su = tid >> 3;
    const int sj = (tid & 7) ^ (su & 7);
    const int g_row = su * 2 + (sj >> 2);
    const int g_col = (sj & 3) * 8;
    const float* gAf0 = Af + (size_t)(m0 + g_row) * HH + g_col;        // rows 0-127
    const float* gAf1 = gAf0 + (size_t)128 * HH;                       // rows 128-255
    __bf16* abw0 = Ab + (size_t)(m0 + g_row) * HH + g_col;
    __bf16* abw1 = abw0 + (size_t)128 * HH;
    const __bf16* gB0 = Wb + (size_t)(n0 + g_row) * HH + g_col;
    const __bf16* gB1 = gB0 + (size_t)128 * HH;
    const int wchunk = wave * 512;    // wave-uniform chunk base (elems)

    // read-side fragment offsets (within an 8192-elem slot)
    int aoff[8], boff[4];
#pragma unroll
    for (int i = 0; i < 8; i++) {
        int frow = wm + i * 16 + l16;
        int r7 = frow & 127;
        int u2 = r7 >> 1;
        int cc = u2 * 8 + (((((r7 & 1) << 2) | quad)) ^ (u2 & 7));
        aoff[i] = (frow >> 7) * 4096 + cc * 8;
    }
#pragma unroll
    for (int j = 0; j < 4; j++) {
        int frow = wn + j * 16 + l16;
        int r7 = frow & 127;
        int u2 = r7 >> 1;
        int cc = u2 * 8 + (((((r7 & 1) << 2) | quad)) ^ (u2 & 7));
        boff[j] = 32768 + (frow >> 7) * 4096 + cc * 8;
    }

#define BGLOAD(slot, koff)                                                              \
    {                                                                                   \
        __bf16* d_ = smem + 32768 + (slot) * 8192 + wchunk;                             \
        __builtin_amdgcn_global_load_lds(GLB(gB0 + (koff)), LDSP(d_), 16, 0, 0);        \
        __builtin_amdgcn_global_load_lds(GLB(gB1 + (koff)), LDSP(d_ + 4096), 16, 0, 0); \
    }
#define AISSUE(K)                                      \
    {                                                  \
        ar0 = *(const float4*)(gAf0 + (K));            \
        ar1 = *(const float4*)(gAf0 + (K) + 4);        \
        ar2 = *(const float4*)(gAf1 + (K));            \
        ar3 = *(const float4*)(gAf1 + (K) + 4);        \
    }
// AWRITE: cvt 16 f32 -> bf16, ds_write both row-halves into slot (linear
// layout identical to old gload_lds), optional global writeback to Ab.
#define AWRITE(x0, x1, x2, x3, slot, K, WBOK)                                           \
    {                                                                                   \
        union { ushort u[8]; uint4 v; } pl_, ph_;                                       \
        pl_.u[0] = f2bf((x0).x); pl_.u[1] = f2bf((x0).y);                               \
        pl_.u[2] = f2bf((x0).z); pl_.u[3] = f2bf((x0).w);                               \
        pl_.u[4] = f2bf((x1).x); pl_.u[5] = f2bf((x1).y);                               \
        pl_.u[6] = f2bf((x1).z); pl_.u[7] = f2bf((x1).w);                               \
        ph_.u[0] = f2bf((x2).x); ph_.u[1] = f2bf((x2).y);                               \
        ph_.u[2] = f2bf((x2).z); ph_.u[3] = f2bf((x2).w);                               \
        ph_.u[4] = f2bf((x3).x); ph_.u[5] = f2bf((x3).y);                               \
        ph_.u[6] = f2bf((x3).z); ph_.u[7] = f2bf((x3).w);                               \
        *(uint4*)(smem + (slot) * 8192 + tid * 8) = pl_.v;                              \
        *(uint4*)(smem + (slot) * 8192 + 4096 + tid * 8) = ph_.v;                       \
        if ((WBOK) && nq == 0) {                                                        \
            *(uint4*)(abw0 + (K)) = pl_.v;                                              \
            *(uint4*)(abw1 + (K)) = ph_.v;                                              \
        }                                                                               \
    }
#define READ_BFR(base)                                     \
    {                                                      \
        bfr[0] = *(const bf16x8*)((base) + boff[0]);       \
        bfr[1] = *(const bf16x8*)((base) + boff[1]);       \
        bfr[2] = *(const bf16x8*)((base) + boff[2]);       \
        bfr[3] = *(const bf16x8*)((base) + boff[3]);       \
    }
#define READ_ALO(base)                                     \
    {                                                      \
        af[0] = *(const bf16x8*)((base) + aoff[0]);        \
        af[1] = *(const bf16x8*)((base) + aoff[1]);        \
        af[2] = *(const bf16x8*)((base) + aoff[2]);        \
        af[3] = *(const bf16x8*)((base) + aoff[3]);        \
    }
#define READ_AHI(base)                                     \
    {                                                      \
        af2[0] = *(const bf16x8*)((base) + aoff[4]);       \
        af2[1] = *(const bf16x8*)((base) + aoff[5]);       \
        af2[2] = *(const bf16x8*)((base) + aoff[6]);       \
        af2[3] = *(const bf16x8*)((base) + aoff[7]);       \
    }
#define MFMA_LO                                                                            \
    _Pragma("unroll") for (int i_ = 0; i_ < 4; i_++)                                       \
        _Pragma("unroll") for (int j_ = 0; j_ < 4; j_++)                                   \
            acc[i_][j_] = __builtin_amdgcn_mfma_f32_16x16x32_bf16(af[i_], bfr[j_], acc[i_][j_], 0, 0, 0);
#define MFMA_HI                                                                            \
    _Pragma("unroll") for (int i_ = 0; i_ < 4; i_++)                                       \
        _Pragma("unroll") for (int j_ = 0; j_ < 4; j_++)                                   \
            acc[i_ + 4][j_] = __builtin_amdgcn_mfma_f32_16x16x32_bf16(af2[i_], bfr[j_], acc[i_ + 4][j_], 0, 0, 0);
#define BAR __builtin_amdgcn_s_barrier()
#define LGKM0 asm volatile("s_waitcnt lgkmcnt(0)" ::: "memory")
#define VMW2 asm volatile("s_waitcnt vmcnt(2)" ::: "memory")
#define VMW8 asm volatile("s_waitcnt vmcnt(8)" ::: "memory")
#define VMW0 asm volatile("s_waitcnt vmcnt(0)" ::: "memory")
#define PRIO1 __builtin_amdgcn_s_setprio(1)
#define PRIO0 __builtin_amdgcn_s_setprio(0)

    // SPAN(P, K1, K2, K3, WB1, WB2): compute K-tile kt (parity P) from slots
    // {2P, 2P+1}. p1: write A(kt+1,k1) [koff K1, issued prev p3], issue
    // A(kt+2,k0) [K2]. p2: gload B(kt+1,k1) [K1]. p3: write A(kt+2,k0) [K2],
    // issue A(kt+2,k1) [K3]. p4: gload B(kt+2,k0) [K2].
#define SPAN(P, K1, K2, K3, WB1, WB2)                \
    {                                                \
        const __bf16* cb0 = smem + (P) * 16384;      \
        const __bf16* cb1 = cb0 + 8192;              \
        /* phase 1 */                                \
        READ_BFR(cb0); READ_ALO(cb0);                \
        VMW2;                                        \
        AWRITE(ar0, ar1, ar2, ar3, (1 - (P)) * 2 + 1, K1, WB1); \
        AISSUE(K2);                                  \
        BAR; LGKM0; PRIO1; MFMA_LO; PRIO0; BAR;      \
        /* phase 2 */                                \
        READ_AHI(cb0);                               \
        BGLOAD((1 - (P)) * 2 + 1, K1);               \
        BAR; LGKM0; PRIO1; MFMA_HI; PRIO0; BAR;      \
        /* phase 3 */                                \
        READ_BFR(cb1); READ_ALO(cb1);                \
        VMW2;                                        \
        AWRITE(ar0, ar1, ar2, ar3, (P) * 2, K2, WB2); \
        AISSUE(K3);                                  \
        BAR; LGKM0; PRIO1; MFMA_LO; PRIO0; BAR;      \
        /* phase 4 */                                \
        READ_AHI(cb1);                               \
        BGLOAD((P) * 2, K2);                         \
        BAR; LGKM0; PRIO1; MFMA_HI; PRIO0; BAR;      \
    }

    bf16x8 af[4], af2[4], bfr[4];
    float4 ar0, ar1, ar2, ar3;

    // ---- prologue: write A(0,k0),A(0,k1),A(1,k0); gload B(0,k0),B(0,k1),
    // B(1,k0); end with areg=A(1,k1)-issued. Loop-entry outstanding:
    // [A(1,k1)x4, B(1,k0)x2] -> p1's VMW2 retires A(1,k1), leaves B(1,k0). ----
    {
        float4 t0, t1, t2, t3, u0, u1, u2, u3;
        t0 = *(const float4*)(gAf0 + 0);  t1 = *(const float4*)(gAf0 + 4);
        t2 = *(const float4*)(gAf1 + 0);  t3 = *(const float4*)(gAf1 + 4);
        u0 = *(const float4*)(gAf0 + 32); u1 = *(const float4*)(gAf0 + 36);
        u2 = *(const float4*)(gAf1 + 32); u3 = *(const float4*)(gAf1 + 36);
        BGLOAD(0, 0);
        BGLOAD(1, 32);
        VMW8;                                   // retire t*
        AWRITE(t0, t1, t2, t3, 0, 0, true);
        t0 = *(const float4*)(gAf0 + 64); t1 = *(const float4*)(gAf0 + 68);
        t2 = *(const float4*)(gAf1 + 64); t3 = *(const float4*)(gAf1 + 68);
        VMW8;                                   // retire u*  (12 -> 8)
        AWRITE(u0, u1, u2, u3, 1, 32, true);
        VMW0;                                   // drain: t*, B(0,k0), B(0,k1)
        AWRITE(t0, t1, t2, t3, 2, 64, true);
        AISSUE(96);                             // areg = A(1,k1)
        BGLOAD(2, 64);                          // B(1,k0)
        LGKM0;
        BAR;
    }

    for (int it = 0; it < 8; ++it) {
        const int kb = it * 128;
        const bool e = (it < 7);
        const int K1a = kb + 96;                // (2it+1,k1) -- always valid
        const int K2a = e ? kb + 128 : 0;       // (2it+2,k0)
        const int K3a = e ? kb + 160 : 0;       // (2it+2,k1)
        const int K1b = e ? kb + 160 : 0;
        const int K2b = e ? kb + 192 : 0;       // (2it+3,k0)
        const int K3b = e ? kb + 224 : 0;       // (2it+3,k1)
        SPAN(0, K1a, K2a, K3a, true, e)
        SPAN(1, K1b, K2b, K3b, e, e)
    }

#undef SPAN
#undef BGLOAD
#undef AISSUE
#undef AWRITE
#undef READ_BFR
#undef READ_ALO
#undef READ_AHI
#undef MFMA_LO
#undef MFMA_HI
#undef BAR
#undef LGKM0
#undef VMW2
#undef VMW8
#undef VMW0
#undef PRIO1
#undef PRIO0

    // epilogue: partial[m] = sum over this block's 256 n of relu(acc + projh)*v
    float ph[4], vv[4];
#pragma unroll
    for (int j = 0; j < 4; j++) {
        int ng = n0 + wn + j * 16 + l16;
        ph[j] = projh[bidx * HH + ng];
        vv[j] = vW[ng];
    }

    // LDS cross-wave reduction buffer in slot A0 (last garbage write to A0 was
    // >=2 barriers ago; __syncthreads drains vmcnt/lgkm anyway).
    float* red = (float*)smem;
    if (tid < 256) red[tid] = 0.f;
    __syncthreads();

#pragma unroll
    for (int i = 0; i < 8; i++) {
        float s[4] = {0.f, 0.f, 0.f, 0.f};
#pragma unroll
        for (int j = 0; j < 4; j++) {
#pragma unroll
            for (int r2 = 0; r2 < 4; r2++) {
                float e = acc[i][j][r2] + ph[j];
                e = e > 0.f ? e : 0.f;
                s[r2] += e * vv[j];
            }
        }
#pragma unroll
        for (int r2 = 0; r2 < 4; r2++) {
            s[r2] += __shfl_xor(s[r2], 1);
            s[r2] += __shfl_xor(s[r2], 2);
            s[r2] += __shfl_xor(s[r2], 4);
            s[r2] += __shfl_xor(s[r2], 8);
        }
        if (l16 == 0) {
#pragma unroll
            for (int r2 = 0; r2 < 4; r2++)
                atomicAdd(&red[wm + i * 16 + quad * 4 + r2], s[r2]);  // LDS atomic
        }
    }
    __syncthreads();
    if (tid < 256) scores_part[(size_t)nq * MM + m0 + tid] = red[tid];
}

// ---------------- fallback GEMM (f32 staging, atomics into scores_part[0]) ----------------
__global__ __launch_bounds__(256) void gemm_scores_f32_kernel(
    const float* __restrict__ A, const float* __restrict__ W,
    const float* __restrict__ projh, const float* __restrict__ vW,
    float* __restrict__ scores)       // scores_part slice 0, pre-zeroed by prep
{
    constexpr int BM = 128, BN = 128, BK = 32, LDT = BK + 8;
    __shared__ __bf16 As[BM * LDT];
    __shared__ __bf16 Bs[BN * LDT];
    const int n0 = blockIdx.x * BN;
    const int m0 = blockIdx.y * BM;
    const int bidx = m0 >> 11;
    const int tid = threadIdx.x;
    const int lane = tid & 63;
    const int wave = tid >> 6;
    const int wm = (wave & 1) * 64;
    const int wn = (wave >> 1) * 64;
    const int quad = lane >> 4;
    const int l16 = lane & 15;
    floatx4 acc[4][4];
    const floatx4 z = {0.f, 0.f, 0.f, 0.f};
#pragma unroll
    for (int i = 0; i < 4; i++)
#pragma unroll
        for (int j = 0; j < 4; j++) acc[i][j] = z;
    int rowT[4], colT[4];
#pragma unroll
    for (int i = 0; i < 4; i++) {
        int fi = tid + 256 * i;
        rowT[i] = fi >> 3;
        colT[i] = (fi & 7) * 4;
    }
    for (int k0 = 0; k0 < HH; k0 += BK) {
        float4 av[4], bv[4];
#pragma unroll
        for (int i = 0; i < 4; i++) {
            av[i] = *(const float4*)(A + (size_t)(m0 + rowT[i]) * HH + k0 + colT[i]);
            bv[i] = *(const float4*)(W + (size_t)(n0 + rowT[i]) * (2 * HH) + HH + k0 + colT[i]);
        }
        __syncthreads();
#pragma unroll
        for (int i = 0; i < 4; i++) {
            ushort4 ua = make_ushort4(f2bf(av[i].x), f2bf(av[i].y), f2bf(av[i].z), f2bf(av[i].w));
            ushort4 ub = make_ushort4(f2bf(bv[i].x), f2bf(bv[i].y), f2bf(bv[i].z), f2bf(bv[i].w));
            *(ushort4*)&As[rowT[i] * LDT + colT[i]] = ua;
            *(ushort4*)&Bs[rowT[i] * LDT + colT[i]] = ub;
        }
        __syncthreads();
        bf16x8 af[4], bf[4];
#pragma unroll
        for (int i = 0; i < 4; i++)
            af[i] = *(const bf16x8*)&As[(wm + i * 16 + l16) * LDT + quad * 8];
#pragma unroll
        for (int j = 0; j < 4; j++)
            bf[j] = *(const bf16x8*)&Bs[(wn + j * 16 + l16) * LDT + quad * 8];
#pragma unroll
        for (int i = 0; i < 4; i++)
#pragma unroll
            for (int j = 0; j < 4; j++)
                acc[i][j] = __builtin_amdgcn_mfma_f32_16x16x32_bf16(af[i], bf[j], acc[i][j], 0, 0, 0);
    }
    float ph[4], vv[4];
#pragma unroll
    for (int j = 0; j < 4; j++) {
        int ng = n0 + wn + j * 16 + l16;
        ph[j] = projh[bidx * HH + ng];
        vv[j] = vW[ng];
    }
#pragma unroll
    for (int i = 0; i < 4; i++) {
        float s[4] = {0.f, 0.f, 0.f, 0.f};
#pragma unroll
        for (int j = 0; j < 4; j++) {
#pragma unroll
            for (int r = 0; r < 4; r++) {
                float e = acc[i][j][r] + ph[j];
                e = e > 0.f ? e : 0.f;
                s[r] += e * vv[j];
            }
        }
#pragma unroll
        for (int r = 0; r < 4; r++) {
            s[r] += __shfl_xor(s[r], 1);
            s[r] += __shfl_xor(s[r], 2);
            s[r] += __shfl_xor(s[r], 4);
            s[r] += __shfl_xor(s[r], 8);
        }
        if (l16 == 0) {
#pragma unroll
            for (int r = 0; r < 4; r++) {
                int mg = m0 + wm + i * 16 + quad * 4 + r;
                atomicAdd(&scores[mg], s[r]);
            }
        }
    }
}

// ---------------- fused softmax + context (context reads bf16 Ab) ----------------
__global__ __launch_bounds__(256) void softmax_context_kernel(
    const __bf16* __restrict__ Ab, const float* __restrict__ scores_part,
    int nparts, float* __restrict__ wout, float* __restrict__ ctx)
{
    int b = blockIdx.x >> 5;
    int sc = blockIdx.x & 31;
    int tid = threadIdx.x;
    const float* srow = scores_part + b * SS;

    // batch scores = sum of partials; max + sumexp (256 thr x 8 covers S=2048)
    float x[8];
    float mx = -1e30f;
#pragma unroll
    for (int i = 0; i < 8; i++) {
        int idx = tid + i * 256;
        float v = srow[idx];
        for (int q = 1; q < nparts; q++) v += srow[(size_t)q * MM + idx];
        x[i] = v; mx = fmaxf(mx, v);
    }
#pragma unroll
    for (int off = 32; off; off >>= 1) mx = fmaxf(mx, __shfl_xor(mx, off));
    __shared__ float redm[4], reds[4];
    if ((tid & 63) == 0) redm[tid >> 6] = mx;
    __syncthreads();
    mx = fmaxf(fmaxf(redm[0], redm[1]), fmaxf(redm[2], redm[3]));
    float sum = 0.f;
#pragma unroll
    for (int i = 0; i < 8; i++) sum += __expf(x[i] - mx);
#pragma unroll
    for (int off = 32; off; off >>= 1) sum += __shfl_xor(sum, off);
    if ((tid & 63) == 0) reds[tid >> 6] = sum;
    __syncthreads();
    float inv = 1.0f / (reds[0] + reds[1] + reds[2] + reds[3]);

    // weights for this 64-row chunk -> LDS + global
    __shared__ float wsm[64];
    if (tid < 64) {
        int idx = sc * 64 + tid;
        float v = srow[idx];
        for (int q = 1; q < nparts; q++) v += srow[(size_t)q * MM + idx];
        float wv = __expf(v - mx) * inv;
        wsm[tid] = wv;
        wout[b * SS + idx] = wv;
    }
    __syncthreads();

    // context partial over 64 rows, bf16 A (4 cols per thread)
    const __bf16* arow = Ab + ((size_t)b * SS + sc * 64) * HH + tid * 4;
    float4 acc = make_float4(0.f, 0.f, 0.f, 0.f);
#pragma unroll 4
    for (int s = 0; s < 64; s++) {
        float w = wsm[s];
        uint2 uv = *(const uint2*)(arow + (size_t)s * HH);
        float a0 = __builtin_bit_cast(float, uv.x << 16);
        float a1 = __builtin_bit_cast(float, uv.x & 0xffff0000u);
        float a2 = __builtin_bit_cast(float, uv.y << 16);
        float a3 = __builtin_bit_cast(float, uv.y & 0xffff0000u);
        acc.x += w * a0; acc.y += w * a1; acc.z += w * a2; acc.w += w * a3;
    }
    float* o = ctx + b * HH + tid * 4;
    atomicAdd(o + 0, acc.x);
    atomicAdd(o + 1, acc.y);
    atomicAdd(o + 2, acc.z);
    atomicAdd(o + 3, acc.w);
}

// f32-A variant for the fallback path (no Ab available)
__global__ __launch_bounds__(256) void softmax_context_f32_kernel(
    const float* __restrict__ A, const float* __restrict__ scores_part,
    float* __restrict__ wout, float* __restrict__ ctx)
{
    int b = blockIdx.x >> 5;
    int sc = blockIdx.x & 31;
    int tid = threadIdx.x;
    const float* srow = scores_part + b * SS;
    float x[8];
    float mx = -1e30f;
#pragma unroll
    for (int i = 0; i < 8; i++) { x[i] = srow[tid + i * 256]; mx = fmaxf(mx, x[i]); }
#pragma unroll
    for (int off = 32; off; off >>= 1) mx = fmaxf(mx, __shfl_xor(mx, off));
    __shared__ float redm[4], reds[4];
    if ((tid & 63) == 0) redm[tid >> 6] = mx;
    __syncthreads();
    mx = fmaxf(fmaxf(redm[0], redm[1]), fmaxf(redm[2], redm[3]));
    float sum = 0.f;
#pragma unroll
    for (int i = 0; i < 8; i++) sum += __expf(x[i] - mx);
#pragma unroll
    for (int off = 32; off; off >>= 1) sum += __shfl_xor(sum, off);
    if ((tid & 63) == 0) reds[tid >> 6] = sum;
    __syncthreads();
    float inv = 1.0f / (reds[0] + reds[1] + reds[2] + reds[3]);
    __shared__ float wsm[64];
    if (tid < 64) {
        float wv = __expf(srow[sc * 64 + tid] - mx) * inv;
        wsm[tid] = wv;
        wout[b * SS + sc * 64 + tid] = wv;
    }
    __syncthreads();
    const float* arow = A + ((size_t)b * SS + sc * 64) * HH + tid * 4;
    float4 acc = make_float4(0.f, 0.f, 0.f, 0.f);
#pragma unroll 4
    for (int s = 0; s < 64; s++) {
        float w = wsm[s];
        float4 v = *(const float4*)(arow + (size_t)s * HH);
        acc.x += w * v.x; acc.y += w * v.y; acc.z += w * v.z; acc.w += w * v.w;
    }
    float* o = ctx + b * HH + tid * 4;
    atomicAdd(o + 0, acc.x);
    atomicAdd(o + 1, acc.y);
    atomicAdd(o + 2, acc.z);
    atomicAdd(o + 3, acc.w);
}

extern "C" void kernel_launch(void* const* d_in, const int* in_sizes, int n_in,
                              void* d_out, int out_size, void* d_ws, size_t ws_size,
                              hipStream_t stream) {
    const float* h    = (const float*)d_in[0];
    // d_in[1] = c (unused by reference)
    const float* a    = (const float*)d_in[2];
    const float* W    = (const float*)d_in[3];
    const float* bias = (const float*)d_in[4];
    const float* vW   = (const float*)d_in[5];
    float* out = (float*)d_out;

    float* projh       = (float*)d_ws;             // 16384 f32   (64 KB)
    float* scores_part = projh + BB * HH;          // 4*32768 f32 (512 KB)
    __bf16* Wb = (__bf16*)(scores_part + 4 * MM);  // 1M bf16     (2 MB)
    __bf16* Ab = Wb + (size_t)HH * HH;             // 33.5M bf16  (67.1 MB)
    const size_t need = (size_t)(BB * HH + 4 * MM) * 4 + (size_t)HH * HH * 2
                      + (size_t)MM * HH * 2;

    if (ws_size >= need) {
        prep_all_kernel<<<336, 256, 0, stream>>>(h, W, bias, projh, Wb, scores_part, out);
        gemm_scores_kernel<<<512, 512, 0, stream>>>(a, Wb, projh, vW, scores_part, Ab);
        softmax_context_kernel<<<BB * 32, 256, 0, stream>>>(
            Ab, scores_part, 4, out + BB * HH, out);
    } else {
        prep_all_kernel<<<336, 256, 0, stream>>>(h, W, bias, projh, Wb, scores_part, out);
        gemm_scores_f32_kernel<<<dim3(HH / 128, MM / 128), 256, 0, stream>>>(
            a, W, projh, vW, scores_part);
        softmax_context_f32_kernel<<<BB * 32, 256, 0, stream>>>(
            a, scores_part, out + BB * HH, out);
    }
}

// Round 3
// 299.662 us; speedup vs baseline: 1.0653x; 1.0653x over previous
//
#include <hip/hip_runtime.h>
#include <hip/hip_bf16.h>

// Problem: B=16, S=2048, H=1024
//   a = encoder_outputs (B,S,H) f32
//   projh[b,o] = sum_h h[b,h]*W[o,h] + bias[o]
//   scores[b,s] = sum_o relu( sum_h a[b,s,h]*W[o,H+h] + projh[b,o] ) * v[o]
//   weights = softmax_s(scores); context[b,h] = sum_s weights[b,s]*a[b,s,h]
// Outputs concat: context (16*1024 f32) then weights (16*2048 f32)
//
// 3 dispatches: prep_all -> gemm (writes 4 score partial slices, no atomics)
//            -> softmax_context (sums partials, softmax, context from bf16 A).
// Round 8: REVERT of the round-7 A-fusion (regressed 2.2x: compiler-inserted
// vmcnt drains before AWRITE's reg-use + writeback store-acks in VMW2 killed
// the pipeline). Back to round-6's all-gload_lds 8-phase counted-vmcnt
// schedule, plus a peeled tail iteration: it=7's 3 garbage half-stages
// (12 gload_lds/thread, ~48MB L2 traffic) removed; tail stages only the real
// (15,k1) half-tile and drains VM8->VM4->VM0. Arithmetic bit-identical.

typedef __bf16 bf16x8 __attribute__((ext_vector_type(8)));
typedef float floatx4 __attribute__((ext_vector_type(4)));

#define BB 16
#define SS 2048
#define HH 1024
#define MM (BB * SS)

#define GLB(p) ((const __attribute__((address_space(1))) void*)(p))
#define LDSP(p) ((__attribute__((address_space(3))) void*)(p))

__device__ inline ushort f2bf(float x) {
    uint32_t u = __builtin_bit_cast(uint32_t, x);
    u += 0x7FFFu + ((u >> 16) & 1u);   // round-to-nearest-even
    return (ushort)(u >> 16);
}

// ---------------- prep_all ----------------
// bids [0,256): projh; [256,320): convert_W; [320,336): zero sp0+ctx;
// [336,16720): convert_A (f32 -> bf16, 33.5M elems).
__global__ __launch_bounds__(256) void prep_all_kernel(
    const float* __restrict__ h, const float* __restrict__ W,
    const float* __restrict__ bias, const float* __restrict__ a,
    float* __restrict__ projh, __bf16* __restrict__ Wb, __bf16* __restrict__ Ab,
    float* __restrict__ sp0, float* __restrict__ ctx)
{
    int bid = blockIdx.x;
    int tid = threadIdx.x;
    if (bid >= 336) {
        size_t i = (size_t)(bid - 336) * 256 + tid;   // 8-elem group
        const float* s = a + i * 8;
        float4 x = *(const float4*)(s);
        float4 y = *(const float4*)(s + 4);
        union { ushort u[8]; uint4 v; } p;
        p.u[0] = f2bf(x.x); p.u[1] = f2bf(x.y); p.u[2] = f2bf(x.z); p.u[3] = f2bf(x.w);
        p.u[4] = f2bf(y.x); p.u[5] = f2bf(y.y); p.u[6] = f2bf(y.z); p.u[7] = f2bf(y.w);
        *(uint4*)(Ab + i * 8) = p.v;
    } else if (bid < 256) {
        // projh: (16,1024) = h(16,1024) x W[:, :H]^T + bias
        int b = bid >> 4;
        int oc = bid & 15;
        __shared__ float hrow[HH];
        *(float4*)&hrow[tid * 4] = *(const float4*)(h + (size_t)b * HH + tid * 4);
        __syncthreads();
        int ol = tid >> 2;           // 0..63
        int kq = tid & 3;            // 0..3 (k quarter)
        int o = oc * 64 + ol;
        const float* wr = W + (size_t)o * (2 * HH) + kq * 256;
        const float* hb = hrow + kq * 256;
        float sum = 0.f;
        for (int k = 0; k < 256; k += 4) {
            float4 wv = *(const float4*)(wr + k);
            sum += hb[k] * wv.x + hb[k + 1] * wv.y + hb[k + 2] * wv.z + hb[k + 3] * wv.w;
        }
        sum += __shfl_xor(sum, 1);
        sum += __shfl_xor(sum, 2);
        if (kq == 0) projh[b * HH + o] = sum + bias[o];
    } else if (bid < 320) {
        // convert W[:, H:2H] -> Wb (1024x1024 bf16)
        int cb = bid - 256;
#pragma unroll
        for (int j = 0; j < 8; j++) {
            int g = cb * 2048 + tid + j * 256;
            int o = g >> 7;
            int k = (g & 127) * 8;
            const float* s = W + (size_t)o * (2 * HH) + HH + k;
            float4 x = *(const float4*)(s);
            float4 y = *(const float4*)(s + 4);
            union { ushort u[8]; uint4 v; } p;
            p.u[0] = f2bf(x.x); p.u[1] = f2bf(x.y); p.u[2] = f2bf(x.z); p.u[3] = f2bf(x.w);
            p.u[4] = f2bf(y.x); p.u[5] = f2bf(y.y); p.u[6] = f2bf(y.z); p.u[7] = f2bf(y.w);
            *(uint4*)(Wb + (size_t)o * HH + k) = p.v;
        }
    } else {
        // zero sp0 (32768 f32, fallback path) and ctx (16384 f32): 16 blocks
        int zb = bid - 320;
        float4 z = make_float4(0.f, 0.f, 0.f, 0.f);
        float* sp = sp0 + zb * 2048 + tid * 8;
        *(float4*)(sp) = z;
        *(float4*)(sp + 4) = z;
        *(float4*)(ctx + zb * 1024 + tid * 4) = z;
    }
}

// ---------------- main GEMM: 256x256 tile, 8 waves, BK=64, 8-phase schedule ----------------
// LDS: A half-K slots 0..3 (each 256 rows x 32 cols = 8192 elems = 16KB), B
// slots 0..3 at +32768. K-tile kt (BK=64) kappa-half kap -> slot 2*(kt&1)+kap.
// Per K-tile span: 4 phases {ds_read subtile | stage 1 half-tile -> barrier ->
// lgkmcnt(0) -> setprio(1) -> 16 MFMA -> setprio(0) -> barrier}; vmcnt(8) only
// at phases 2 and 4 (3 half-tiles always in flight; never drained mid-loop).
// Tail (kt=14,15) is peeled: stages only (15,k1)@992, drains VM8->VM4->VM0.
__global__ __launch_bounds__(512, 2) void gemm_scores_kernel(
    const __bf16* __restrict__ Ab,    // (32768,1024) bf16
    const __bf16* __restrict__ Wb,    // (1024,1024) bf16 (cols H..2H of W)
    const float* __restrict__ projh,  // (16,1024) f32
    const float* __restrict__ vW,     // (1024) f32
    float* __restrict__ scores_part)  // (4, 32768) f32
{
    __shared__ __bf16 smem[65536];    // 128 KB

    const int bid = blockIdx.x;
    const int m0 = (((bid >> 5) << 3) + (bid & 7)) * 256;  // 128 M-tiles
    const int nq = (bid >> 3) & 3;    // 4 blocks sharing an A M-tile differ in
    const int n0 = nq * 256;          // bits 3-4 -> same XCD (L2 A-tile share)
    const int bidx = m0 >> 11;        // batch index (256 divides 2048)

    const int tid = threadIdx.x;
    const int lane = tid & 63;
    const int wave = tid >> 6;        // 0..7
    const int wm = (wave & 1) * 128;  // wave tile: 128 (M) x 64 (N)
    const int wn = (wave >> 1) * 64;
    const int quad = lane >> 4;
    const int l16 = lane & 15;

    floatx4 acc[8][4];
    const floatx4 z = {0.f, 0.f, 0.f, 0.f};
#pragma unroll
    for (int i = 0; i < 8; i++)
#pragma unroll
        for (int j = 0; j < 4; j++) acc[i][j] = z;

    // staging thread map (XOR-swizzled global source, linear LDS dest)
    const int su = tid >> 3;
    const int sj = (tid & 7) ^ (su & 7);
    const int g_row = su * 2 + (sj >> 2);
    const int g_col = (sj & 3) * 8;
    const __bf16* gA0 = Ab + (size_t)(m0 + g_row) * HH + g_col;
    const __bf16* gA1 = gA0 + (size_t)128 * HH;
    const __bf16* gB0 = Wb + (size_t)(n0 + g_row) * HH + g_col;
    const __bf16* gB1 = gB0 + (size_t)128 * HH;
    const int wchunk = wave * 512;    // wave-uniform chunk base (elems)

    // read-side fragment offsets (within an 8192-elem slot; matching swizzle)
    int aoff[8], boff[4];
#pragma unroll
    for (int i = 0; i < 8; i++) {
        int frow = wm + i * 16 + l16;
        int r7 = frow & 127;
        int u2 = r7 >> 1;
        int cc = u2 * 8 + (((((r7 & 1) << 2) | quad)) ^ (u2 & 7));
        aoff[i] = (frow >> 7) * 4096 + cc * 8;
    }
#pragma unroll
    for (int j = 0; j < 4; j++) {
        int frow = wn + j * 16 + l16;
        int r7 = frow & 127;
        int u2 = r7 >> 1;
        int cc = u2 * 8 + (((((r7 & 1) << 2) | quad)) ^ (u2 & 7));
        boff[j] = 32768 + (frow >> 7) * 4096 + cc * 8;
    }

#define STAGE_A(slot, koff)                                                             \
    {                                                                                   \
        __bf16* d_ = smem + (slot) * 8192 + wchunk;                                     \
        __builtin_amdgcn_global_load_lds(GLB(gA0 + (koff)), LDSP(d_), 16, 0, 0);        \
        __builtin_amdgcn_global_load_lds(GLB(gA1 + (koff)), LDSP(d_ + 4096), 16, 0, 0); \
    }
#define STAGE_B(slot, koff)                                                             \
    {                                                                                   \
        __bf16* d_ = smem + 32768 + (slot) * 8192 + wchunk;                             \
        __builtin_amdgcn_global_load_lds(GLB(gB0 + (koff)), LDSP(d_), 16, 0, 0);        \
        __builtin_amdgcn_global_load_lds(GLB(gB1 + (koff)), LDSP(d_ + 4096), 16, 0, 0); \
    }
#define READ_BFR(base)                                     \
    {                                                      \
        bfr[0] = *(const bf16x8*)((base) + boff[0]);       \
        bfr[1] = *(const bf16x8*)((base) + boff[1]);       \
        bfr[2] = *(const bf16x8*)((base) + boff[2]);       \
        bfr[3] = *(const bf16x8*)((base) + boff[3]);       \
    }
#define READ_ALO(base)                                     \
    {                                                      \
        af[0] = *(const bf16x8*)((base) + aoff[0]);        \
        af[1] = *(const bf16x8*)((base) + aoff[1]);        \
        af[2] = *(const bf16x8*)((base) + aoff[2]);        \
        af[3] = *(const bf16x8*)((base) + aoff[3]);        \
    }
#define READ_AHI(base)                                     \
    {                                                      \
        af2[0] = *(const bf16x8*)((base) + aoff[4]);       \
        af2[1] = *(const bf16x8*)((base) + aoff[5]);       \
        af2[2] = *(const bf16x8*)((base) + aoff[6]);       \
        af2[3] = *(const bf16x8*)((base) + aoff[7]);       \
    }
#define MFMA_LO                                                                            \
    _Pragma("unroll") for (int i_ = 0; i_ < 4; i_++)                                       \
        _Pragma("unroll") for (int j_ = 0; j_ < 4; j_++)                                   \
            acc[i_][j_] = __builtin_amdgcn_mfma_f32_16x16x32_bf16(af[i_], bfr[j_], acc[i_][j_], 0, 0, 0);
#define MFMA_HI                                                                            \
    _Pragma("unroll") for (int i_ = 0; i_ < 4; i_++)                                       \
        _Pragma("unroll") for (int j_ = 0; j_ < 4; j_++)                                   \
            acc[i_ + 4][j_] = __builtin_amdgcn_mfma_f32_16x16x32_bf16(af2[i_], bfr[j_], acc[i_ + 4][j_], 0, 0, 0);
#define BAR __builtin_amdgcn_s_barrier()
#define LGKM0 asm volatile("s_waitcnt lgkmcnt(0)" ::: "memory")
#define VM8 asm volatile("s_waitcnt vmcnt(8)" ::: "memory")
#define VM4 asm volatile("s_waitcnt vmcnt(4)" ::: "memory")
#define VM0 asm volatile("s_waitcnt vmcnt(0)" ::: "memory")
#define PRIO1 __builtin_amdgcn_s_setprio(1)
#define PRIO0 __builtin_amdgcn_s_setprio(0)

    // SPAN(P, K1, K2): compute K-tile kt (parity P) from slots {2P, 2P+1};
    // stage (kt+1,k1)->slot 2(1-P)+1 at p1/p2, (kt+2,k0)->slot 2P at p3/p4.
#define SPAN(P, K1, K2)                              \
    {                                                \
        const __bf16* cb0 = smem + (P) * 16384;      \
        const __bf16* cb1 = cb0 + 8192;              \
        /* phase 1 */                                \
        READ_BFR(cb0); READ_ALO(cb0);                \
        STAGE_A((1 - (P)) * 2 + 1, K1);              \
        BAR; LGKM0; PRIO1; MFMA_LO; PRIO0; BAR;      \
        /* phase 2 */                                \
        READ_AHI(cb0);                               \
        STAGE_B((1 - (P)) * 2 + 1, K1);              \
        VM8;                                         \
        BAR; LGKM0; PRIO1; MFMA_HI; PRIO0; BAR;      \
        /* phase 3 */                                \
        READ_BFR(cb1); READ_ALO(cb1);                \
        STAGE_A((P) * 2, K2);                        \
        BAR; LGKM0; PRIO1; MFMA_LO; PRIO0; BAR;      \
        /* phase 4 */                                \
        READ_AHI(cb1);                               \
        STAGE_B((P) * 2, K2);                        \
        VM8;                                         \
        BAR; LGKM0; PRIO1; MFMA_HI; PRIO0; BAR;      \
    }

    bf16x8 af[4], af2[4], bfr[4];

    // prologue: K-tile0 (k0,k1) + K-tile1 (k0); retire K-tile0 k0 -> 8 in flight
    STAGE_A(0, 0);  STAGE_B(0, 0);     // kt0 k0 -> slots A0/B0
    STAGE_A(1, 32); STAGE_B(1, 32);    // kt0 k1 -> slots A1/B1
    STAGE_A(2, 64); STAGE_B(2, 64);    // kt1 k0 -> slots A2/B2
    VM8;                                // (0,k0) landed
    BAR;

    // main loop: spans kt=0..13 (all staged offsets real; max koff 960)
    for (int it = 0; it < 7; ++it) {
        const int kb = it * 128;
        SPAN(0, kb + 96, kb + 128)
        SPAN(1, kb + 160, kb + 192)
    }

    // ---- peeled tail: K-tiles 14,15. Entry outstanding (ledger):
    // [A(14,k1)2, B(14,k1)2, A(15,k0)2, B(15,k0)2]; (14,k0) already retired.
    // Only (15,k1)@koff 992 remains to stage (-> slot 3).
    {
        const __bf16* cb0 = smem;            // slot0 = (14,k0)
        const __bf16* cb1 = smem + 8192;     // slot1 = (14,k1)
        const __bf16* cb2 = smem + 16384;    // slot2 = (15,k0)
        const __bf16* cb3 = smem + 24576;    // slot3 = (15,k1)
        // span14 p1
        READ_BFR(cb0); READ_ALO(cb0);
        STAGE_A(3, 992);
        BAR; LGKM0; PRIO1; MFMA_LO; PRIO0; BAR;
        // span14 p2: VM8 retires (14,k1) [read next phase]
        READ_AHI(cb0);
        STAGE_B(3, 992);
        VM8;
        BAR; LGKM0; PRIO1; MFMA_HI; PRIO0; BAR;
        // span14 p3: VM4 retires (15,k0) [read at span15 p1]
        READ_BFR(cb1); READ_ALO(cb1);
        VM4;
        BAR; LGKM0; PRIO1; MFMA_LO; PRIO0; BAR;
        // span14 p4: VM0 drains (15,k1) [read at span15 p3]
        READ_AHI(cb1);
        VM0;
        BAR; LGKM0; PRIO1; MFMA_HI; PRIO0; BAR;
        // span15 (no stages, no waits beyond lgkm)
        READ_BFR(cb2); READ_ALO(cb2);
        BAR; LGKM0; PRIO1; MFMA_LO; PRIO0; BAR;
        READ_AHI(cb2);
        BAR; LGKM0; PRIO1; MFMA_HI; PRIO0; BAR;
        READ_BFR(cb3); READ_ALO(cb3);
        BAR; LGKM0; PRIO1; MFMA_LO; PRIO0; BAR;
        READ_AHI(cb3);
        LGKM0; PRIO1; MFMA_HI; PRIO0;
    }

#undef SPAN
#undef STAGE_A
#undef STAGE_B
#undef READ_BFR
#undef READ_ALO
#undef READ_AHI
#undef MFMA_LO
#undef MFMA_HI
#undef BAR
#undef LGKM0
#undef VM8
#undef VM4
#undef VM0
#undef PRIO1
#undef PRIO0

    // epilogue: partial[m] = sum over this block's 256 n of relu(acc + projh)*v
    float ph[4], vv[4];
#pragma unroll
    for (int j = 0; j < 4; j++) {
        int ng = n0 + wn + j * 16 + l16;
        ph[j] = projh[bidx * HH + ng];
        vv[j] = vW[ng];
    }

    // LDS cross-wave reduction buffer in slot A0 (last read was span14; no
    // in-flight loads target it; __syncthreads orders the reuse).
    float* red = (float*)smem;
    __syncthreads();
    if (tid < 256) red[tid] = 0.f;
    __syncthreads();

#pragma unroll
    for (int i = 0; i < 8; i++) {
        float s[4] = {0.f, 0.f, 0.f, 0.f};
#pragma unroll
        for (int j = 0; j < 4; j++) {
#pragma unroll
            for (int r2 = 0; r2 < 4; r2++) {
                float e = acc[i][j][r2] + ph[j];
                e = e > 0.f ? e : 0.f;
                s[r2] += e * vv[j];
            }
        }
#pragma unroll
        for (int r2 = 0; r2 < 4; r2++) {
            s[r2] += __shfl_xor(s[r2], 1);
            s[r2] += __shfl_xor(s[r2], 2);
            s[r2] += __shfl_xor(s[r2], 4);
            s[r2] += __shfl_xor(s[r2], 8);
        }
        if (l16 == 0) {
#pragma unroll
            for (int r2 = 0; r2 < 4; r2++)
                atomicAdd(&red[wm + i * 16 + quad * 4 + r2], s[r2]);  // LDS atomic
        }
    }
    __syncthreads();
    if (tid < 256) scores_part[(size_t)nq * MM + m0 + tid] = red[tid];
}

// ---------------- fallback GEMM (f32 staging, atomics into scores_part[0]) ----------------
__global__ __launch_bounds__(256) void gemm_scores_f32_kernel(
    const float* __restrict__ A, const float* __restrict__ W,
    const float* __restrict__ projh, const float* __restrict__ vW,
    float* __restrict__ scores)       // scores_part slice 0, pre-zeroed by prep
{
    constexpr int BM = 128, BN = 128, BK = 32, LDT = BK + 8;
    __shared__ __bf16 As[BM * LDT];
    __shared__ __bf16 Bs[BN * LDT];
    const int n0 = blockIdx.x * BN;
    const int m0 = blockIdx.y * BM;
    const int bidx = m0 >> 11;
    const int tid = threadIdx.x;
    const int lane = tid & 63;
    const int wave = tid >> 6;
    const int wm = (wave & 1) * 64;
    const int wn = (wave >> 1) * 64;
    const int quad = lane >> 4;
    const int l16 = lane & 15;
    floatx4 acc[4][4];
    const floatx4 z = {0.f, 0.f, 0.f, 0.f};
#pragma unroll
    for (int i = 0; i < 4; i++)
#pragma unroll
        for (int j = 0; j < 4; j++) acc[i][j] = z;
    int rowT[4], colT[4];
#pragma unroll
    for (int i = 0; i < 4; i++) {
        int fi = tid + 256 * i;
        rowT[i] = fi >> 3;
        colT[i] = (fi & 7) * 4;
    }
    for (int k0 = 0; k0 < HH; k0 += BK) {
        float4 av[4], bv[4];
#pragma unroll
        for (int i = 0; i < 4; i++) {
            av[i] = *(const float4*)(A + (size_t)(m0 + rowT[i]) * HH + k0 + colT[i]);
            bv[i] = *(const float4*)(W + (size_t)(n0 + rowT[i]) * (2 * HH) + HH + k0 + colT[i]);
        }
        __syncthreads();
#pragma unroll
        for (int i = 0; i < 4; i++) {
            ushort4 ua = make_ushort4(f2bf(av[i].x), f2bf(av[i].y), f2bf(av[i].z), f2bf(av[i].w));
            ushort4 ub = make_ushort4(f2bf(bv[i].x), f2bf(bv[i].y), f2bf(bv[i].z), f2bf(bv[i].w));
            *(ushort4*)&As[rowT[i] * LDT + colT[i]] = ua;
            *(ushort4*)&Bs[rowT[i] * LDT + colT[i]] = ub;
        }
        __syncthreads();
        bf16x8 af[4], bf[4];
#pragma unroll
        for (int i = 0; i < 4; i++)
            af[i] = *(const bf16x8*)&As[(wm + i * 16 + l16) * LDT + quad * 8];
#pragma unroll
        for (int j = 0; j < 4; j++)
            bf[j] = *(const bf16x8*)&Bs[(wn + j * 16 + l16) * LDT + quad * 8];
#pragma unroll
        for (int i = 0; i < 4; i++)
#pragma unroll
            for (int j = 0; j < 4; j++)
                acc[i][j] = __builtin_amdgcn_mfma_f32_16x16x32_bf16(af[i], bf[j], acc[i][j], 0, 0, 0);
    }
    float ph[4], vv[4];
#pragma unroll
    for (int j = 0; j < 4; j++) {
        int ng = n0 + wn + j * 16 + l16;
        ph[j] = projh[bidx * HH + ng];
        vv[j] = vW[ng];
    }
#pragma unroll
    for (int i = 0; i < 4; i++) {
        float s[4] = {0.f, 0.f, 0.f, 0.f};
#pragma unroll
        for (int j = 0; j < 4; j++) {
#pragma unroll
            for (int r = 0; r < 4; r++) {
                float e = acc[i][j][r] + ph[j];
                e = e > 0.f ? e : 0.f;
                s[r] += e * vv[j];
            }
        }
#pragma unroll
        for (int r = 0; r < 4; r++) {
            s[r] += __shfl_xor(s[r], 1);
            s[r] += __shfl_xor(s[r], 2);
            s[r] += __shfl_xor(s[r], 4);
            s[r] += __shfl_xor(s[r], 8);
        }
        if (l16 == 0) {
#pragma unroll
            for (int r = 0; r < 4; r++) {
                int mg = m0 + wm + i * 16 + quad * 4 + r;
                atomicAdd(&scores[mg], s[r]);
            }
        }
    }
}

// ---------------- fused softmax + context (context reads bf16 Ab) ----------------
// 512 blocks = 16 b x 32 s-chunks of 64 rows. Each block sums nparts score
// partials, computes its batch's softmax stats (redundant, L2-hot), writes its
// 64-element weights slice, then accumulates context partials via atomics.
__global__ __launch_bounds__(256) void softmax_context_kernel(
    const __bf16* __restrict__ Ab, const float* __restrict__ scores_part,
    int nparts, float* __restrict__ wout, float* __restrict__ ctx)
{
    int b = blockIdx.x >> 5;
    int sc = blockIdx.x & 31;
    int tid = threadIdx.x;
    const float* srow = scores_part + b * SS;

    // batch scores = sum of partials; max + sumexp (256 thr x 8 covers S=2048)
    float x[8];
    float mx = -1e30f;
#pragma unroll
    for (int i = 0; i < 8; i++) {
        int idx = tid + i * 256;
        float v = srow[idx];
        for (int q = 1; q < nparts; q++) v += srow[(size_t)q * MM + idx];
        x[i] = v; mx = fmaxf(mx, v);
    }
#pragma unroll
    for (int off = 32; off; off >>= 1) mx = fmaxf(mx, __shfl_xor(mx, off));
    __shared__ float redm[4], reds[4];
    if ((tid & 63) == 0) redm[tid >> 6] = mx;
    __syncthreads();
    mx = fmaxf(fmaxf(redm[0], redm[1]), fmaxf(redm[2], redm[3]));
    float sum = 0.f;
#pragma unroll
    for (int i = 0; i < 8; i++) sum += __expf(x[i] - mx);
#pragma unroll
    for (int off = 32; off; off >>= 1) sum += __shfl_xor(sum, off);
    if ((tid & 63) == 0) reds[tid >> 6] = sum;
    __syncthreads();
    float inv = 1.0f / (reds[0] + reds[1] + reds[2] + reds[3]);

    // weights for this 64-row chunk -> LDS + global
    __shared__ float wsm[64];
    if (tid < 64) {
        int idx = sc * 64 + tid;
        float v = srow[idx];
        for (int q = 1; q < nparts; q++) v += srow[(size_t)q * MM + idx];
        float wv = __expf(v - mx) * inv;
        wsm[tid] = wv;
        wout[b * SS + idx] = wv;
    }
    __syncthreads();

    // context partial over 64 rows, bf16 A (4 cols per thread)
    const __bf16* arow = Ab + ((size_t)b * SS + sc * 64) * HH + tid * 4;
    float4 acc = make_float4(0.f, 0.f, 0.f, 0.f);
#pragma unroll 4
    for (int s = 0; s < 64; s++) {
        float w = wsm[s];
        uint2 uv = *(const uint2*)(arow + (size_t)s * HH);
        float a0 = __builtin_bit_cast(float, uv.x << 16);
        float a1 = __builtin_bit_cast(float, uv.x & 0xffff0000u);
        float a2 = __builtin_bit_cast(float, uv.y << 16);
        float a3 = __builtin_bit_cast(float, uv.y & 0xffff0000u);
        acc.x += w * a0; acc.y += w * a1; acc.z += w * a2; acc.w += w * a3;
    }
    float* o = ctx + b * HH + tid * 4;
    atomicAdd(o + 0, acc.x);
    atomicAdd(o + 1, acc.y);
    atomicAdd(o + 2, acc.z);
    atomicAdd(o + 3, acc.w);
}

// f32-A variant for the fallback path (no Ab available)
__global__ __launch_bounds__(256) void softmax_context_f32_kernel(
    const float* __restrict__ A, const float* __restrict__ scores_part,
    float* __restrict__ wout, float* __restrict__ ctx)
{
    int b = blockIdx.x >> 5;
    int sc = blockIdx.x & 31;
    int tid = threadIdx.x;
    const float* srow = scores_part + b * SS;
    float x[8];
    float mx = -1e30f;
#pragma unroll
    for (int i = 0; i < 8; i++) { x[i] = srow[tid + i * 256]; mx = fmaxf(mx, x[i]); }
#pragma unroll
    for (int off = 32; off; off >>= 1) mx = fmaxf(mx, __shfl_xor(mx, off));
    __shared__ float redm[4], reds[4];
    if ((tid & 63) == 0) redm[tid >> 6] = mx;
    __syncthreads();
    mx = fmaxf(fmaxf(redm[0], redm[1]), fmaxf(redm[2], redm[3]));
    float sum = 0.f;
#pragma unroll
    for (int i = 0; i < 8; i++) sum += __expf(x[i] - mx);
#pragma unroll
    for (int off = 32; off; off >>= 1) sum += __shfl_xor(sum, off);
    if ((tid & 63) == 0) reds[tid >> 6] = sum;
    __syncthreads();
    float inv = 1.0f / (reds[0] + reds[1] + reds[2] + reds[3]);
    __shared__ float wsm[64];
    if (tid < 64) {
        float wv = __expf(srow[sc * 64 + tid] - mx) * inv;
        wsm[tid] = wv;
        wout[b * SS + sc * 64 + tid] = wv;
    }
    __syncthreads();
    const float* arow = A + ((size_t)b * SS + sc * 64) * HH + tid * 4;
    float4 acc = make_float4(0.f, 0.f, 0.f, 0.f);
#pragma unroll 4
    for (int s = 0; s < 64; s++) {
        float w = wsm[s];
        float4 v = *(const float4*)(arow + (size_t)s * HH);
        acc.x += w * v.x; acc.y += w * v.y; acc.z += w * v.z; acc.w += w * v.w;
    }
    float* o = ctx + b * HH + tid * 4;
    atomicAdd(o + 0, acc.x);
    atomicAdd(o + 1, acc.y);
    atomicAdd(o + 2, acc.z);
    atomicAdd(o + 3, acc.w);
}

extern "C" void kernel_launch(void* const* d_in, const int* in_sizes, int n_in,
                              void* d_out, int out_size, void* d_ws, size_t ws_size,
                              hipStream_t stream) {
    const float* h    = (const float*)d_in[0];
    // d_in[1] = c (unused by reference)
    const float* a    = (const float*)d_in[2];
    const float* W    = (const float*)d_in[3];
    const float* bias = (const float*)d_in[4];
    const float* vW   = (const float*)d_in[5];
    float* out = (float*)d_out;

    float* projh       = (float*)d_ws;             // 16384 f32   (64 KB)
    float* scores_part = projh + BB * HH;          // 4*32768 f32 (512 KB)
    __bf16* Wb = (__bf16*)(scores_part + 4 * MM);  // 1M bf16     (2 MB)
    __bf16* Ab = Wb + (size_t)HH * HH;             // 33.5M bf16  (67.1 MB)
    const size_t need = (size_t)(BB * HH + 4 * MM) * 4 + (size_t)HH * HH * 2
                      + (size_t)MM * HH * 2;

    if (ws_size >= need) {
        prep_all_kernel<<<336 + MM * HH / 8 / 256, 256, 0, stream>>>(
            h, W, bias, a, projh, Wb, Ab, scores_part, out);
        gemm_scores_kernel<<<512, 512, 0, stream>>>(Ab, Wb, projh, vW, scores_part);
        softmax_context_kernel<<<BB * 32, 256, 0, stream>>>(
            Ab, scores_part, 4, out + BB * HH, out);
    } else {
        prep_all_kernel<<<336, 256, 0, stream>>>(h, W, bias, a, projh, Wb, Ab, scores_part, out);
        gemm_scores_f32_kernel<<<dim3(HH / 128, MM / 128), 256, 0, stream>>>(
            a, W, projh, vW, scores_part);
        softmax_context_f32_kernel<<<BB * 32, 256, 0, stream>>>(
            a, scores_part, out + BB * HH, out);
    }
}

// Round 4
// 287.950 us; speedup vs baseline: 1.1086x; 1.0407x over previous
//
#include <hip/hip_runtime.h>
#include <hip/hip_bf16.h>

// Problem: B=16, S=2048, H=1024
//   a = encoder_outputs (B,S,H) f32
//   projh[b,o] = sum_h h[b,h]*W[o,h] + bias[o]
//   scores[b,s] = sum_o relu( sum_h a[b,s,h]*W[o,H+h] + projh[b,o] ) * v[o]
//   weights = softmax_s(scores); context[b,h] = sum_s weights[b,s]*a[b,s,h]
// Outputs concat: context (16*1024 f32) then weights (16*2048 f32)
//
// Round 9: A-conversion pass eliminated. The gemm stages f32 A directly to
// LDS via global_load_lds (only gload_lds in the K-loop -- the round-1-proven
// machinery; round-2's reg-staging failure mode is structurally absent) and
// converts to bf16 between ds_read and MFMA. BK=32, 3-deep ring, 144 KB LDS,
// one vmcnt(6) per K-tile. A-read bank conflicts fixed by both-sides XOR
// swizzle (linear LDS dest, pre-swizzled global source chunk (l&7)^(l>>3),
// read offset (quad*32+sub*16)^((row&7)<<4)). Ab buffer gone; softmax reads
// f32 A (L3-warm from the gemm).

typedef __bf16 bf16x8 __attribute__((ext_vector_type(8)));
typedef float floatx4 __attribute__((ext_vector_type(4)));

#define BB 16
#define SS 2048
#define HH 1024
#define MM (BB * SS)

#define GLB(p) ((const __attribute__((address_space(1))) void*)(p))
#define LDSP(p) ((__attribute__((address_space(3))) void*)(p))

__device__ inline ushort f2bf(float x) {
    uint32_t u = __builtin_bit_cast(uint32_t, x);
    u += 0x7FFFu + ((u >> 16) & 1u);   // round-to-nearest-even
    return (ushort)(u >> 16);
}

// ---------------- prep_all ----------------
// bids [0,256): projh; [256,320): convert_W; [320,336): zero sp0+ctx.
__global__ __launch_bounds__(256) void prep_all_kernel(
    const float* __restrict__ h, const float* __restrict__ W,
    const float* __restrict__ bias,
    float* __restrict__ projh, __bf16* __restrict__ Wb,
    float* __restrict__ sp0, float* __restrict__ ctx)
{
    int bid = blockIdx.x;
    int tid = threadIdx.x;
    if (bid < 256) {
        // projh: (16,1024) = h(16,1024) x W[:, :H]^T + bias
        int b = bid >> 4;
        int oc = bid & 15;
        __shared__ float hrow[HH];
        *(float4*)&hrow[tid * 4] = *(const float4*)(h + (size_t)b * HH + tid * 4);
        __syncthreads();
        int ol = tid >> 2;           // 0..63
        int kq = tid & 3;            // 0..3 (k quarter)
        int o = oc * 64 + ol;
        const float* wr = W + (size_t)o * (2 * HH) + kq * 256;
        const float* hb = hrow + kq * 256;
        float sum = 0.f;
        for (int k = 0; k < 256; k += 4) {
            float4 wv = *(const float4*)(wr + k);
            sum += hb[k] * wv.x + hb[k + 1] * wv.y + hb[k + 2] * wv.z + hb[k + 3] * wv.w;
        }
        sum += __shfl_xor(sum, 1);
        sum += __shfl_xor(sum, 2);
        if (kq == 0) projh[b * HH + o] = sum + bias[o];
    } else if (bid < 320) {
        // convert W[:, H:2H] -> Wb (1024x1024 bf16)
        int cb = bid - 256;
#pragma unroll
        for (int j = 0; j < 8; j++) {
            int g = cb * 2048 + tid + j * 256;
            int o = g >> 7;
            int k = (g & 127) * 8;
            const float* s = W + (size_t)o * (2 * HH) + HH + k;
            float4 x = *(const float4*)(s);
            float4 y = *(const float4*)(s + 4);
            union { ushort u[8]; uint4 v; } p;
            p.u[0] = f2bf(x.x); p.u[1] = f2bf(x.y); p.u[2] = f2bf(x.z); p.u[3] = f2bf(x.w);
            p.u[4] = f2bf(y.x); p.u[5] = f2bf(y.y); p.u[6] = f2bf(y.z); p.u[7] = f2bf(y.w);
            *(uint4*)(Wb + (size_t)o * HH + k) = p.v;
        }
    } else {
        // zero sp0 (32768 f32, fallback path) and ctx (16384 f32): 16 blocks
        int zb = bid - 320;
        float4 z = make_float4(0.f, 0.f, 0.f, 0.f);
        float* sp = sp0 + zb * 2048 + tid * 8;
        *(float4*)(sp) = z;
        *(float4*)(sp + 4) = z;
        *(float4*)(ctx + zb * 1024 + tid * 4) = z;
    }
}

// ---------------- main GEMM: 256x256 tile, 8 waves, BK=32, 3-deep ring ----------------
// LDS: A slots 0..2 (256 rows x 32 f32 = 32 KB each, row = 128 B, linear,
// column data pre-swizzled at the global source); B slots 0..2 (256 x 32 bf16
// = 16 KB each, round-1 layout) at byte 98304. Total 144 KB.
// Per K-tile kt (slot kt%3), 2 phases:
//  p1: read B-frags(4 b128) + A-LO f32(8 b128); stage A(kt+2); BAR; lgkm0;
//      cvt; setprio1; 16 MFMA_LO; setprio0; BAR.
//  p2: read A-HI f32(8 b128); stage B(kt+2); vmcnt(6); BAR; lgkm0; cvt;
//      setprio1; 16 MFMA_HI; setprio0; BAR.
// Ledger: at p2 after stage-B issue, outstanding = [A(kt+1)4, B(kt+1)2,
// A(kt+2)4, B(kt+2)2]; VM6 retires (kt+1)'s pair (read next K-tile, after 2
// more barriers). Prologue stages tiles 0,1 then VM6 retires tile 0.
// Tail: kt=30 no stage + VM0; kt=31 clean.
__global__ __launch_bounds__(512, 2) void gemm_scores_kernel(
    const float* __restrict__ Af,     // (32768,1024) f32 encoder outputs
    const __bf16* __restrict__ Wb,    // (1024,1024) bf16 (cols H..2H of W)
    const float* __restrict__ projh,  // (16,1024) f32
    const float* __restrict__ vW,     // (1024) f32
    float* __restrict__ scores_part)  // (4, 32768) f32
{
    __shared__ __align__(16) char smem_raw[147456];   // 144 KB
    __bf16* sB = (__bf16*)(smem_raw + 98304);

    const int bid = blockIdx.x;
    const int m0 = (((bid >> 5) << 3) + (bid & 7)) * 256;  // 128 M-tiles
    const int nq = (bid >> 3) & 3;    // 4 blocks sharing an A M-tile differ in
    const int n0 = nq * 256;          // bits 3-4 -> same XCD (L2 A-tile share)
    const int bidx = m0 >> 11;        // batch index (256 divides 2048)

    const int tid = threadIdx.x;
    const int lane = tid & 63;
    const int wave = tid >> 6;        // 0..7
    const int wm = (wave & 1) * 128;  // wave tile: 128 (M) x 64 (N)
    const int wn = (wave >> 1) * 64;
    const int quad = lane >> 4;
    const int l16 = lane & 15;

    floatx4 acc[8][4];
    const floatx4 z = {0.f, 0.f, 0.f, 0.f};
#pragma unroll
    for (int i = 0; i < 8; i++)
#pragma unroll
        for (int j = 0; j < 4; j++) acc[i][j] = z;

    // ---- A staging source map (f32, source-side swizzle, linear LDS dest).
    // Op q of wave w covers rows q*64+w*8 .. +8; lane l -> row +(l>>3), LDS
    // chunk (l&7); global chunk (l&7)^(l>>3) (undone on the read side).
    const int rb = lane >> 3;                    // 0..7
    const int cchunk = ((lane & 7) ^ rb) * 4;    // float index of 16B chunk
    const float* gAq0 = Af + (size_t)(m0 +   0 + wave * 8 + rb) * HH + cchunk;
    const float* gAq1 = Af + (size_t)(m0 +  64 + wave * 8 + rb) * HH + cchunk;
    const float* gAq2 = Af + (size_t)(m0 + 128 + wave * 8 + rb) * HH + cchunk;
    const float* gAq3 = Af + (size_t)(m0 + 192 + wave * 8 + rb) * HH + cchunk;

    // ---- B staging source map (bf16, round-1 XOR swizzle, linear LDS dest)
    const int su = tid >> 3;
    const int sj = (tid & 7) ^ (su & 7);
    const int g_row = su * 2 + (sj >> 2);
    const int g_col = (sj & 3) * 8;
    const __bf16* gB0 = Wb + (size_t)(n0 + g_row) * HH + g_col;
    const __bf16* gB1 = gB0 + (size_t)128 * HH;

    // ---- A read offsets: byte = row*128 + ((quad*32 + sub*16) ^ ((row&7)<<4)).
    // row&7 == l16&7 for all frags (wm, i*16 are multiples of 8).
    const int axL = (quad * 32) ^ ((l16 & 7) << 4);
    const int axH = axL ^ 16;
    int arow[8];
#pragma unroll
    for (int i = 0; i < 8; i++) arow[i] = (wm + i * 16 + l16) * 128;

    // ---- B read offsets (slot-relative, round-1 formula)
    int boff[4];
#pragma unroll
    for (int j = 0; j < 4; j++) {
        int frow = wn + j * 16 + l16;
        int r7 = frow & 127;
        int u2 = r7 >> 1;
        int cc = u2 * 8 + (((((r7 & 1) << 2) | quad)) ^ (u2 & 7));
        boff[j] = (frow >> 7) * 4096 + cc * 8;
    }

#define STAGE_A(S, KF)                                                                       \
    {                                                                                        \
        char* dA_ = smem_raw + (S) * 32768 + wave * 1024;                                    \
        __builtin_amdgcn_global_load_lds(GLB(gAq0 + (KF)), LDSP(dA_), 16, 0, 0);             \
        __builtin_amdgcn_global_load_lds(GLB(gAq1 + (KF)), LDSP(dA_ + 8192), 16, 0, 0);      \
        __builtin_amdgcn_global_load_lds(GLB(gAq2 + (KF)), LDSP(dA_ + 16384), 16, 0, 0);     \
        __builtin_amdgcn_global_load_lds(GLB(gAq3 + (KF)), LDSP(dA_ + 24576), 16, 0, 0);     \
    }
#define STAGE_B(S, KF)                                                                       \
    {                                                                                        \
        __bf16* dB_ = sB + (S) * 8192 + wave * 512;                                          \
        __builtin_amdgcn_global_load_lds(GLB(gB0 + (KF)), LDSP(dB_), 16, 0, 0);              \
        __builtin_amdgcn_global_load_lds(GLB(gB1 + (KF)), LDSP(dB_ + 4096), 16, 0, 0);       \
    }
#define CVT8(dst, L, H)                                                     \
    {                                                                       \
        dst[0] = (__bf16)(L).x; dst[1] = (__bf16)(L).y;                     \
        dst[2] = (__bf16)(L).z; dst[3] = (__bf16)(L).w;                     \
        dst[4] = (__bf16)(H).x; dst[5] = (__bf16)(H).y;                     \
        dst[6] = (__bf16)(H).z; dst[7] = (__bf16)(H).w;                     \
    }
#define MFMA_LO                                                                            \
    _Pragma("unroll") for (int i_ = 0; i_ < 4; i_++)                                       \
        _Pragma("unroll") for (int j_ = 0; j_ < 4; j_++)                                   \
            acc[i_][j_] = __builtin_amdgcn_mfma_f32_16x16x32_bf16(af[i_], bfr[j_], acc[i_][j_], 0, 0, 0);
#define MFMA_HI                                                                            \
    _Pragma("unroll") for (int i_ = 0; i_ < 4; i_++)                                       \
        _Pragma("unroll") for (int j_ = 0; j_ < 4; j_++)                                   \
            acc[i_ + 4][j_] = __builtin_amdgcn_mfma_f32_16x16x32_bf16(af2[i_], bfr[j_], acc[i_ + 4][j_], 0, 0, 0);
#define BAR __builtin_amdgcn_s_barrier()
#define LGKM0 asm volatile("s_waitcnt lgkmcnt(0)" ::: "memory")
#define VM6 asm volatile("s_waitcnt vmcnt(6)" ::: "memory")
#define VM0 asm volatile("s_waitcnt vmcnt(0)" ::: "memory")
#define NOPW
#define PRIO1 __builtin_amdgcn_s_setprio(1)
#define PRIO0 __builtin_amdgcn_s_setprio(0)

    // KTILE(SC, SN, KF, DOST, VMW_): compute K-tile in slot SC; if DOST stage
    // (kt+2) into slot SN at element offset KF (floats for A, bf16 for B --
    // numerically equal). VMW_ placed at p2 after the B-stage issue.
#define KTILE(SC, SN, KF, DOST, VMW_)                                        \
    {                                                                        \
        const char* ab_ = smem_raw + (SC) * 32768;                           \
        const __bf16* bb_ = sB + (SC) * 8192;                                \
        /* phase 1 */                                                        \
        bfr[0] = *(const bf16x8*)(bb_ + boff[0]);                            \
        bfr[1] = *(const bf16x8*)(bb_ + boff[1]);                            \
        bfr[2] = *(const bf16x8*)(bb_ + boff[2]);                            \
        bfr[3] = *(const bf16x8*)(bb_ + boff[3]);                            \
        floatx4 aL0 = *(const floatx4*)(ab_ + arow[0] + axL);                \
        floatx4 aH0 = *(const floatx4*)(ab_ + arow[0] + axH);                \
        floatx4 aL1 = *(const floatx4*)(ab_ + arow[1] + axL);                \
        floatx4 aH1 = *(const floatx4*)(ab_ + arow[1] + axH);                \
        floatx4 aL2 = *(const floatx4*)(ab_ + arow[2] + axL);                \
        floatx4 aH2 = *(const floatx4*)(ab_ + arow[2] + axH);                \
        floatx4 aL3 = *(const floatx4*)(ab_ + arow[3] + axL);                \
        floatx4 aH3 = *(const floatx4*)(ab_ + arow[3] + axH);                \
        if (DOST) STAGE_A(SN, KF);                                           \
        BAR; LGKM0;                                                          \
        CVT8(af[0], aL0, aH0); CVT8(af[1], aL1, aH1);                        \
        CVT8(af[2], aL2, aH2); CVT8(af[3], aL3, aH3);                        \
        PRIO1; MFMA_LO; PRIO0; BAR;                                          \
        /* phase 2 */                                                        \
        floatx4 cL0 = *(const floatx4*)(ab_ + arow[4] + axL);                \
        floatx4 cH0 = *(const floatx4*)(ab_ + arow[4] + axH);                \
        floatx4 cL1 = *(const floatx4*)(ab_ + arow[5] + axL);                \
        floatx4 cH1 = *(const floatx4*)(ab_ + arow[5] + axH);                \
        floatx4 cL2 = *(const floatx4*)(ab_ + arow[6] + axL);                \
        floatx4 cH2 = *(const floatx4*)(ab_ + arow[6] + axH);                \
        floatx4 cL3 = *(const floatx4*)(ab_ + arow[7] + axL);                \
        floatx4 cH3 = *(const floatx4*)(ab_ + arow[7] + axH);                \
        if (DOST) STAGE_B(SN, KF);                                           \
        VMW_;                                                                \
        BAR; LGKM0;                                                          \
        CVT8(af2[0], cL0, cH0); CVT8(af2[1], cL1, cH1);                      \
        CVT8(af2[2], cL2, cH2); CVT8(af2[3], cL3, cH3);                      \
        PRIO1; MFMA_HI; PRIO0; BAR;                                          \
    }

    bf16x8 af[4], af2[4], bfr[4];

    // prologue: tiles 0,1 staged; VM6 retires tile 0 (keeps A1+B1 = 6)
    STAGE_A(0, 0);
    STAGE_B(0, 0);
    STAGE_A(1, 32);
    STAGE_B(1, 32);
    VM6;
    BAR;

    // kt = 0..29 in groups of 3 (slots 0,1,2); stage targets kt+2 <= 31
    for (int g = 0; g < 10; ++g) {
        const int kf0 = (3 * g + 2) * 32;
        KTILE(0, 2, kf0, 1, VM6)
        KTILE(1, 0, kf0 + 32, 1, VM6)
        KTILE(2, 1, kf0 + 64, 1, VM6)
    }
    // kt = 30 (slot 0): nothing left to stage; drain the tile-31 pair
    KTILE(0, 2, 0, 0, VM0)
    // kt = 31 (slot 1): clean
    KTILE(1, 0, 0, 0, NOPW)

#undef KTILE
#undef STAGE_A
#undef STAGE_B
#undef CVT8
#undef MFMA_LO
#undef MFMA_HI
#undef BAR
#undef LGKM0
#undef VM6
#undef VM0
#undef NOPW
#undef PRIO1
#undef PRIO0

    // epilogue: partial[m] = sum over this block's 256 n of relu(acc + projh)*v
    float ph[4], vv[4];
#pragma unroll
    for (int j = 0; j < 4; j++) {
        int ng = n0 + wn + j * 16 + l16;
        ph[j] = projh[bidx * HH + ng];
        vv[j] = vW[ng];
    }

    // LDS cross-wave reduction buffer at slot A0 (no in-flight loads remain;
    // __syncthreads orders the reuse).
    float* red = (float*)smem_raw;
    __syncthreads();
    if (tid < 256) red[tid] = 0.f;
    __syncthreads();

#pragma unroll
    for (int i = 0; i < 8; i++) {
        float s[4] = {0.f, 0.f, 0.f, 0.f};
#pragma unroll
        for (int j = 0; j < 4; j++) {
#pragma unroll
            for (int r2 = 0; r2 < 4; r2++) {
                float e = acc[i][j][r2] + ph[j];
                e = e > 0.f ? e : 0.f;
                s[r2] += e * vv[j];
            }
        }
#pragma unroll
        for (int r2 = 0; r2 < 4; r2++) {
            s[r2] += __shfl_xor(s[r2], 1);
            s[r2] += __shfl_xor(s[r2], 2);
            s[r2] += __shfl_xor(s[r2], 4);
            s[r2] += __shfl_xor(s[r2], 8);
        }
        if (l16 == 0) {
#pragma unroll
            for (int r2 = 0; r2 < 4; r2++)
                atomicAdd(&red[wm + i * 16 + quad * 4 + r2], s[r2]);  // LDS atomic
        }
    }
    __syncthreads();
    if (tid < 256) scores_part[(size_t)nq * MM + m0 + tid] = red[tid];
}

// ---------------- fallback GEMM (f32 staging, atomics into scores_part[0]) ----------------
__global__ __launch_bounds__(256) void gemm_scores_f32_kernel(
    const float* __restrict__ A, const float* __restrict__ W,
    const float* __restrict__ projh, const float* __restrict__ vW,
    float* __restrict__ scores)       // scores_part slice 0, pre-zeroed by prep
{
    constexpr int BM = 128, BN = 128, BK = 32, LDT = BK + 8;
    __shared__ __bf16 As[BM * LDT];
    __shared__ __bf16 Bs[BN * LDT];
    const int n0 = blockIdx.x * BN;
    const int m0 = blockIdx.y * BM;
    const int bidx = m0 >> 11;
    const int tid = threadIdx.x;
    const int lane = tid & 63;
    const int wave = tid >> 6;
    const int wm = (wave & 1) * 64;
    const int wn = (wave >> 1) * 64;
    const int quad = lane >> 4;
    const int l16 = lane & 15;
    floatx4 acc[4][4];
    const floatx4 z = {0.f, 0.f, 0.f, 0.f};
#pragma unroll
    for (int i = 0; i < 4; i++)
#pragma unroll
        for (int j = 0; j < 4; j++) acc[i][j] = z;
    int rowT[4], colT[4];
#pragma unroll
    for (int i = 0; i < 4; i++) {
        int fi = tid + 256 * i;
        rowT[i] = fi >> 3;
        colT[i] = (fi & 7) * 4;
    }
    for (int k0 = 0; k0 < HH; k0 += BK) {
        float4 av[4], bv[4];
#pragma unroll
        for (int i = 0; i < 4; i++) {
            av[i] = *(const float4*)(A + (size_t)(m0 + rowT[i]) * HH + k0 + colT[i]);
            bv[i] = *(const float4*)(W + (size_t)(n0 + rowT[i]) * (2 * HH) + HH + k0 + colT[i]);
        }
        __syncthreads();
#pragma unroll
        for (int i = 0; i < 4; i++) {
            ushort4 ua = make_ushort4(f2bf(av[i].x), f2bf(av[i].y), f2bf(av[i].z), f2bf(av[i].w));
            ushort4 ub = make_ushort4(f2bf(bv[i].x), f2bf(bv[i].y), f2bf(bv[i].z), f2bf(bv[i].w));
            *(ushort4*)&As[rowT[i] * LDT + colT[i]] = ua;
            *(ushort4*)&Bs[rowT[i] * LDT + colT[i]] = ub;
        }
        __syncthreads();
        bf16x8 af[4], bf[4];
#pragma unroll
        for (int i = 0; i < 4; i++)
            af[i] = *(const bf16x8*)&As[(wm + i * 16 + l16) * LDT + quad * 8];
#pragma unroll
        for (int j = 0; j < 4; j++)
            bf[j] = *(const bf16x8*)&Bs[(wn + j * 16 + l16) * LDT + quad * 8];
#pragma unroll
        for (int i = 0; i < 4; i++)
#pragma unroll
            for (int j = 0; j < 4; j++)
                acc[i][j] = __builtin_amdgcn_mfma_f32_16x16x32_bf16(af[i], bf[j], acc[i][j], 0, 0, 0);
    }
    float ph[4], vv[4];
#pragma unroll
    for (int j = 0; j < 4; j++) {
        int ng = n0 + wn + j * 16 + l16;
        ph[j] = projh[bidx * HH + ng];
        vv[j] = vW[ng];
    }
#pragma unroll
    for (int i = 0; i < 4; i++) {
        float s[4] = {0.f, 0.f, 0.f, 0.f};
#pragma unroll
        for (int j = 0; j < 4; j++) {
#pragma unroll
            for (int r = 0; r < 4; r++) {
                float e = acc[i][j][r] + ph[j];
                e = e > 0.f ? e : 0.f;
                s[r] += e * vv[j];
            }
        }
#pragma unroll
        for (int r = 0; r < 4; r++) {
            s[r] += __shfl_xor(s[r], 1);
            s[r] += __shfl_xor(s[r], 2);
            s[r] += __shfl_xor(s[r], 4);
            s[r] += __shfl_xor(s[r], 8);
        }
        if (l16 == 0) {
#pragma unroll
            for (int r = 0; r < 4; r++) {
                int mg = m0 + wm + i * 16 + quad * 4 + r;
                atomicAdd(&scores[mg], s[r]);
            }
        }
    }
}

// ---------------- fused softmax + context (f32 A, nparts score partials) ----------------
// 512 blocks = 16 b x 32 s-chunks of 64 rows. Each block sums nparts score
// partials, computes its batch's softmax stats (redundant, L2-hot), writes its
// 64-element weights slice, then accumulates context partials via atomics.
__global__ __launch_bounds__(256) void softmax_context_kernel(
    const float* __restrict__ A, const float* __restrict__ scores_part,
    int nparts, float* __restrict__ wout, float* __restrict__ ctx)
{
    int b = blockIdx.x >> 5;
    int sc = blockIdx.x & 31;
    int tid = threadIdx.x;
    const float* srow = scores_part + b * SS;

    float x[8];
    float mx = -1e30f;
#pragma unroll
    for (int i = 0; i < 8; i++) {
        int idx = tid + i * 256;
        float v = srow[idx];
        for (int q = 1; q < nparts; q++) v += srow[(size_t)q * MM + idx];
        x[i] = v; mx = fmaxf(mx, v);
    }
#pragma unroll
    for (int off = 32; off; off >>= 1) mx = fmaxf(mx, __shfl_xor(mx, off));
    __shared__ float redm[4], reds[4];
    if ((tid & 63) == 0) redm[tid >> 6] = mx;
    __syncthreads();
    mx = fmaxf(fmaxf(redm[0], redm[1]), fmaxf(redm[2], redm[3]));
    float sum = 0.f;
#pragma unroll
    for (int i = 0; i < 8; i++) sum += __expf(x[i] - mx);
#pragma unroll
    for (int off = 32; off; off >>= 1) sum += __shfl_xor(sum, off);
    if ((tid & 63) == 0) reds[tid >> 6] = sum;
    __syncthreads();
    float inv = 1.0f / (reds[0] + reds[1] + reds[2] + reds[3]);

    __shared__ float wsm[64];
    if (tid < 64) {
        int idx = sc * 64 + tid;
        float v = srow[idx];
        for (int q = 1; q < nparts; q++) v += srow[(size_t)q * MM + idx];
        float wv = __expf(v - mx) * inv;
        wsm[tid] = wv;
        wout[b * SS + idx] = wv;
    }
    __syncthreads();

    const float* arow = A + ((size_t)b * SS + sc * 64) * HH + tid * 4;
    float4 acc = make_float4(0.f, 0.f, 0.f, 0.f);
#pragma unroll 4
    for (int s = 0; s < 64; s++) {
        float w = wsm[s];
        float4 v = *(const float4*)(arow + (size_t)s * HH);
        acc.x += w * v.x; acc.y += w * v.y; acc.z += w * v.z; acc.w += w * v.w;
    }
    float* o = ctx + b * HH + tid * 4;
    atomicAdd(o + 0, acc.x);
    atomicAdd(o + 1, acc.y);
    atomicAdd(o + 2, acc.z);
    atomicAdd(o + 3, acc.w);
}

extern "C" void kernel_launch(void* const* d_in, const int* in_sizes, int n_in,
                              void* d_out, int out_size, void* d_ws, size_t ws_size,
                              hipStream_t stream) {
    const float* h    = (const float*)d_in[0];
    // d_in[1] = c (unused by reference)
    const float* a    = (const float*)d_in[2];
    const float* W    = (const float*)d_in[3];
    const float* bias = (const float*)d_in[4];
    const float* vW   = (const float*)d_in[5];
    float* out = (float*)d_out;

    float* projh       = (float*)d_ws;             // 16384 f32   (64 KB)
    float* scores_part = projh + BB * HH;          // 4*32768 f32 (512 KB)
    __bf16* Wb = (__bf16*)(scores_part + 4 * MM);  // 1M bf16     (2 MB)
    const size_t need = (size_t)(BB * HH + 4 * MM) * 4 + (size_t)HH * HH * 2;

    if (ws_size >= need) {
        prep_all_kernel<<<336, 256, 0, stream>>>(h, W, bias, projh, Wb, scores_part, out);
        gemm_scores_kernel<<<512, 512, 0, stream>>>(a, Wb, projh, vW, scores_part);
        softmax_context_kernel<<<BB * 32, 256, 0, stream>>>(
            a, scores_part, 4, out + BB * HH, out);
    } else {
        // (need is ~2.6 MB; this path should never trigger, but keep it safe)
        prep_all_kernel<<<336, 256, 0, stream>>>(h, W, bias, projh, Wb, scores_part, out);
        gemm_scores_f32_kernel<<<dim3(HH / 128, MM / 128), 256, 0, stream>>>(
            a, W, projh, vW, scores_part);
        softmax_context_kernel<<<BB * 32, 256, 0, stream>>>(
            a, scores_part, 1, out + BB * HH, out);
    }
}